// Round 11
// baseline (457.246 us; speedup 1.0000x reference)
//
#include <hip/hip_runtime.h>
#include <cstdint>

static constexpr int N = 100000;
static constexpr int D = 64;
static constexpr int E = 1250000;
static constexpr int NBKT = N / 32;            // 3125 coarse buckets (dst>>5)
static constexpr int NQ = N / 32;              // 3125 gather node-groups of 32
static constexpr int GGRID = 1563;             // gather grid: 2 balanced iters
static constexpr float EPS = 1e-5f;

// ---------------- threefry2x32, 20 rounds, key = (0, 42) --------------------
__device__ __forceinline__ uint32_t rotl32(uint32_t x, int r) {
    return (x << r) | (x >> (32 - r));
}

__device__ __forceinline__ void threefry2x32_k42(uint32_t& x0, uint32_t& x1) {
    const uint32_t ks0 = 0u, ks1 = 42u, ks2 = 0x1BD11BDAu ^ 0u ^ 42u;
    x0 += ks0; x1 += ks1;
#define TF_R4(a,b,c,d) \
    x0 += x1; x1 = rotl32(x1,a); x1 ^= x0; \
    x0 += x1; x1 = rotl32(x1,b); x1 ^= x0; \
    x0 += x1; x1 = rotl32(x1,c); x1 ^= x0; \
    x0 += x1; x1 = rotl32(x1,d); x1 ^= x0;
    TF_R4(13,15,26,6);  x0 += ks1; x1 += ks2 + 1u;
    TF_R4(17,29,16,24); x0 += ks2; x1 += ks0 + 2u;
    TF_R4(13,15,26,6);  x0 += ks0; x1 += ks1 + 3u;
    TF_R4(17,29,16,24); x0 += ks1; x1 += ks2 + 4u;
    TF_R4(13,15,26,6);  x0 += ks2; x1 += ks0 + 5u;
#undef TF_R4
}

// ---------------- bf16 helpers ---------------------------------------------
__device__ __forceinline__ uint32_t f2bf(float f) {          // RNE
    const uint32_t u = __float_as_uint(f);
    return (u + 0x7FFFu + ((u >> 16) & 1u)) >> 16;
}
__device__ __forceinline__ float bfl(uint32_t u) { return __uint_as_float(u << 16); }
__device__ __forceinline__ float bfh(uint32_t u) { return __uint_as_float(u & 0xFFFF0000u); }

__device__ __forceinline__ int load_idx(const uint32_t* raw, bool is64, int i) {
    return (int)(is64 ? raw[2u * (uint32_t)i] : raw[(uint32_t)i]);
}

// per-block int64 detection (first 256 odd words; broadcast reads, cheap)
__device__ __forceinline__ bool detect64(const uint32_t* raw) {
    __shared__ int s_is64;
    if (threadIdx.x < 64) {
        bool ok = true;
        #pragma unroll
        for (int k = 0; k < 4; ++k)
            ok &= (raw[(threadIdx.x * 4 + k) * 2 + 1] == 0u);
        const unsigned long long m = __ballot(ok);
        if (threadIdx.x == 0) s_is64 = (m == ~0ULL) ? 1 : 0;
    }
    __syncthreads();
    return s_is64 != 0;
}

// ------- zero sums + dh + dcur + bcnt (contiguous u32 span) ----------------
__global__ __launch_bounds__(256) void k_zero(uint32_t* __restrict__ z, int n32) {
    const int i = blockIdx.x * 256 + threadIdx.x;
    if (i < n32) z[i] = 0u;
}

// ------- bucket histogram of dst (3125 coarse buckets) ---------------------
__global__ __launch_bounds__(256) void k_prep(const uint32_t* __restrict__ raw,
                                              uint32_t* __restrict__ bcnt) {
    const bool is64 = detect64(raw);
    for (int e = blockIdx.x * 256 + threadIdx.x; e < E; e += gridDim.x * 256) {
        const uint32_t d = (uint32_t)load_idx(raw, is64, E + e);
        atomicAdd(&bcnt[d >> 5], 1u);
    }
}

// ------- single-block scan of bcnt[3125] → bptr[3126] + bcur copy ----------
__global__ __launch_bounds__(1024) void k_bscan(const uint32_t* __restrict__ bcnt,
                                                uint32_t* __restrict__ bptr,
                                                uint32_t* __restrict__ bcur) {
    __shared__ uint32_t ls[1024];
    const int t = threadIdx.x;
    uint32_t v[4];
    const int base_i = t * 4;
    #pragma unroll
    for (int k = 0; k < 4; ++k)
        v[k] = (base_i + k < NBKT) ? bcnt[base_i + k] : 0u;
    const uint32_t tsum = v[0] + v[1] + v[2] + v[3];
    ls[t] = tsum;
    __syncthreads();
    for (int off = 1; off < 1024; off <<= 1) {
        const uint32_t u = (t >= off) ? ls[t - off] : 0u;
        __syncthreads();
        ls[t] += u;
        __syncthreads();
    }
    uint32_t run = ls[t] - tsum;                 // exclusive prefix
    #pragma unroll
    for (int k = 0; k < 4; ++k) {
        if (base_i + k < NBKT) { bptr[base_i + k] = run; bcur[base_i + k] = run; }
        run += v[k];
    }
    if (t == 1023) bptr[NBKT] = ls[1023];        // == E
}

// ------- scatter edges into bucket regions, packed (src<<5)|(dst&31) -------
__global__ __launch_bounds__(256) void k_bsort(const uint32_t* __restrict__ raw,
                                               uint32_t* __restrict__ bcur,
                                               uint32_t* __restrict__ edata) {
    const bool is64 = detect64(raw);
    for (int e = blockIdx.x * 256 + threadIdx.x; e < E; e += gridDim.x * 256) {
        const uint32_t s = (uint32_t)load_idx(raw, is64, e);
        const uint32_t d = (uint32_t)load_idx(raw, is64, E + e);
        const uint32_t pos = atomicAdd(&bcur[d >> 5], 1u);
        edata[pos] = (s << 5) | (d & 31u);       // src<2^17 → fits 22 bits
    }
}

// ------- per-bucket LDS counting sort → csr / rowptr / dinv / dh -----------
__global__ __launch_bounds__(256) void k_csr(const uint32_t* __restrict__ edata,
                                             const uint32_t* __restrict__ bptr,
                                             uint32_t* __restrict__ csr,
                                             uint32_t* __restrict__ rowptr,
                                             float* __restrict__ dinv,
                                             uint32_t* __restrict__ dh) {
    __shared__ uint32_t ed[1024], stage[1024];
    __shared__ uint32_t hcnt[32], hofs[32], hcur[32];
    __shared__ uint32_t dhist[128];
    const int bkt = blockIdx.x;
    const int tid = threadIdx.x;
    const uint32_t base = bptr[bkt];
    const uint32_t cnt  = bptr[bkt + 1] - base;
    if (tid < 32) hcnt[tid] = 0u;
    if (tid < 128) dhist[tid] = 0u;
    __syncthreads();
    for (uint32_t i = tid; i < cnt; i += 256) {
        const uint32_t e = edata[base + i];
        if (i < 1024u) ed[i] = e;
        atomicAdd(&hcnt[e & 31u], 1u);
    }
    __syncthreads();
    if (tid == 0) {
        uint32_t run = 0;
        #pragma unroll
        for (int n = 0; n < 32; ++n) { hofs[n] = run; run += hcnt[n]; }
    }
    __syncthreads();
    if (tid < 32) {
        const int node = bkt * 32 + tid;
        rowptr[node] = base + hofs[tid];
        dinv[node] = rsqrtf((float)(hcnt[tid] + 1u));
        hcur[tid] = hofs[tid];
        atomicAdd(&dhist[min(hcnt[tid], 127u)], 1u);
    }
    if (bkt == 0 && tid == 0) rowptr[N] = (uint32_t)E;
    __syncthreads();
    for (uint32_t i = tid; i < cnt; i += 256) {
        const uint32_t e = (i < 1024u) ? ed[i] : edata[base + i];
        const uint32_t p = atomicAdd(&hcur[e & 31u], 1u);
        const uint32_t s = e >> 5;
        if (p < 1024u) stage[p] = s;
        else           csr[base + p] = s;        // overflow: rare direct write
    }
    __syncthreads();
    const uint32_t m = min(cnt, 1024u);
    for (uint32_t i = tid; i < m; i += 256) csr[base + i] = stage[i];  // coalesced
    if (tid < 128 && dhist[tid] != 0u) atomicAdd(&dh[tid], dhist[tid]);
}

// ------- scan degree histogram dh[128] → dcur ------------------------------
__global__ __launch_bounds__(128) void k_dscan(const uint32_t* __restrict__ dh,
                                               uint32_t* __restrict__ dcur) {
    __shared__ uint32_t ls[128];
    const int t = threadIdx.x;
    const uint32_t hv = dh[t];
    ls[t] = hv;
    __syncthreads();
    for (int off = 1; off < 128; off <<= 1) {
        const uint32_t u = (t >= off) ? ls[t - off] : 0u;
        __syncthreads();
        ls[t] += u;
        __syncthreads();
    }
    dcur[t] = ls[t] - hv;                        // exclusive bucket start
}

// ------- counting-sort nodes by degree → perm (LDS-aggregated) -------------
__global__ __launch_bounds__(256) void k_perm(const uint32_t* __restrict__ rowptr,
                                              uint32_t* __restrict__ dcur,
                                              uint32_t* __restrict__ perm) {
    __shared__ uint32_t lcnt[128], lbase[128];
    const int tid = threadIdx.x;
    if (tid < 128) lcnt[tid] = 0u;
    __syncthreads();
    const int i = blockIdx.x * 256 + tid;
    int d = 0; uint32_t lrank = 0;
    if (i < N) {
        d = (int)min(rowptr[i + 1] - rowptr[i], 127u);
        lrank = atomicAdd(&lcnt[d], 1u);
    }
    __syncthreads();
    if (tid < 128 && lcnt[tid] != 0u) lbase[tid] = atomicAdd(&dcur[tid], lcnt[tid]);
    __syncthreads();
    if (i < N) perm[lbase[d] + lrank] = (uint32_t)i;
}

// ------- hs = bf16( (x @ W) * dinv[row] )  — dinv folded into GEMM ---------
__global__ __launch_bounds__(256) void k_gemm(const float* __restrict__ x,
                                              const float* __restrict__ W,
                                              const float* __restrict__ dinv,
                                              uint32_t* __restrict__ hs) {  // packed 2×bf16
    __shared__ float Ws[64 * 64];
    const int tid = threadIdx.x;
    #pragma unroll
    for (int i = 0; i < 4; ++i) {
        const int off = tid * 4 + i * 1024;
        *reinterpret_cast<float4*>(&Ws[off]) =
            *reinterpret_cast<const float4*>(&W[off]);
    }
    __syncthreads();
    const int row = blockIdx.x * 256 + tid;
    if (row >= N) return;
    const float* xr = x + (size_t)row * 64;
    float4 acc[16];
    #pragma unroll
    for (int i = 0; i < 16; ++i) acc[i] = make_float4(0.f, 0.f, 0.f, 0.f);
    for (int k = 0; k < 64; k += 4) {
        const float4 xv = *reinterpret_cast<const float4*>(xr + k);
        const float xs[4] = {xv.x, xv.y, xv.z, xv.w};
        #pragma unroll
        for (int kk = 0; kk < 4; ++kk) {
            const float s = xs[kk];
            const float4* wr = reinterpret_cast<const float4*>(&Ws[(k + kk) * 64]);
            #pragma unroll
            for (int d4 = 0; d4 < 16; ++d4) {
                const float4 w = wr[d4];
                acc[d4].x += s * w.x; acc[d4].y += s * w.y;
                acc[d4].z += s * w.z; acc[d4].w += s * w.w;
            }
        }
    }
    const float sc = dinv[row];
    uint32_t pack[32];
    #pragma unroll
    for (int i = 0; i < 16; ++i) {
        pack[2 * i]     = f2bf(acc[i].x * sc) | (f2bf(acc[i].y * sc) << 16);
        pack[2 * i + 1] = f2bf(acc[i].z * sc) | (f2bf(acc[i].w * sc) << 16);
    }
    uint4* hr = reinterpret_cast<uint4*>(hs + (size_t)row * 32);
    #pragma unroll
    for (int i = 0; i < 8; ++i) hr[i] = reinterpret_cast<const uint4*>(pack)[i];
}

// ---- gather: 8-lane group/dst, depth-8 batches, degree-sorted, fused BN ---
__global__ __launch_bounds__(256) void k_gather_bn(const uint32_t* __restrict__ hsu,
                                                   const float* __restrict__ dinv,
                                                   const uint32_t* __restrict__ rowptr,
                                                   const uint32_t* __restrict__ csr,
                                                   const uint32_t* __restrict__ perm,
                                                   const float* __restrict__ b,
                                                   float* __restrict__ out,
                                                   double* __restrict__ sums) {
    const int tid = threadIdx.x;
    const int grp = tid >> 3;            // 0..31: one dst node per 8-lane group
    const int sub = tid & 7;             // dims sub*8 .. sub*8+7
    float bb[8];
    {
        const float4 b0 = *reinterpret_cast<const float4*>(&b[sub * 8]);
        const float4 b1 = *reinterpret_cast<const float4*>(&b[sub * 8 + 4]);
        bb[0] = b0.x; bb[1] = b0.y; bb[2] = b0.z; bb[3] = b0.w;
        bb[4] = b1.x; bb[5] = b1.y; bb[6] = b1.z; bb[7] = b1.w;
    }
    float regS[8], regQ[8];
    #pragma unroll
    for (int k = 0; k < 8; ++k) { regS[k] = 0.f; regQ[k] = 0.f; }

    for (int q = blockIdx.x; q < NQ; q += GGRID) {       // ≤2 balanced iters
        const int d = (int)perm[q * 32 + grp];
        const uint32_t beg = rowptr[d], end = rowptr[d + 1];
        float a[8];
        {
            const uint4 sv = *reinterpret_cast<const uint4*>(&hsu[(size_t)d * 32 + sub * 4]);
            a[0] = bfl(sv.x); a[1] = bfh(sv.x); a[2] = bfl(sv.y); a[3] = bfh(sv.y);
            a[4] = bfl(sv.z); a[5] = bfh(sv.z); a[6] = bfl(sv.w); a[7] = bfh(sv.w);
        }
        uint32_t j = beg;
        while (j + 8 <= end) {                           // depth-8 batches
            const uint32_t sj = csr[j + (uint32_t)sub];  // 8 lanes: 8 edge ids
            uint4 v[8];
            #pragma unroll
            for (int k = 0; k < 8; ++k) {
                const int s = __shfl((int)sj, k, 8);     // group-local broadcast
                v[k] = *reinterpret_cast<const uint4*>(&hsu[(size_t)s * 32 + sub * 4]);
            }
            #pragma unroll
            for (int k = 0; k < 8; ++k) {
                a[0] += bfl(v[k].x); a[1] += bfh(v[k].x);
                a[2] += bfl(v[k].y); a[3] += bfh(v[k].y);
                a[4] += bfl(v[k].z); a[5] += bfh(v[k].z);
                a[6] += bfl(v[k].w); a[7] += bfh(v[k].w);
            }
            j += 8;
        }
        if (j < end) {                                   // tail < 8
            const uint32_t sj = (j + (uint32_t)sub < end) ? csr[j + (uint32_t)sub] : 0u;
            const int r = (int)(end - j);
            for (int k = 0; k < r; ++k) {
                const int s = __shfl((int)sj, k, 8);
                const uint4 vv = *reinterpret_cast<const uint4*>(&hsu[(size_t)s * 32 + sub * 4]);
                a[0] += bfl(vv.x); a[1] += bfh(vv.x);
                a[2] += bfl(vv.y); a[3] += bfh(vv.y);
                a[4] += bfl(vv.z); a[5] += bfh(vv.z);
                a[6] += bfl(vv.w); a[7] += bfh(vv.w);
            }
        }
        const float dd = dinv[d];
        float o[8];
        #pragma unroll
        for (int k = 0; k < 8; ++k) {
            o[k] = a[k] * dd + bb[k];
            regS[k] += o[k]; regQ[k] += o[k] * o[k];
        }
        const float4 o0 = make_float4(o[0], o[1], o[2], o[3]);
        const float4 o1 = make_float4(o[4], o[5], o[6], o[7]);
        *reinterpret_cast<float4*>(&out[(size_t)d * 64 + sub * 8])     = o0;
        *reinterpret_cast<float4*>(&out[(size_t)d * 64 + sub * 8 + 4]) = o1;
    }
    __shared__ float lsS[32][64], lsQ[32][64];
    #pragma unroll
    for (int k = 0; k < 8; ++k) {
        lsS[grp][sub * 8 + k] = regS[k];
        lsQ[grp][sub * 8 + k] = regQ[k];
    }
    __syncthreads();
    if (tid < 64) {
        float s = 0.f, qq = 0.f;
        #pragma unroll
        for (int g2 = 0; g2 < 32; ++g2) { s += lsS[g2][tid]; qq += lsQ[g2][tid]; }
        atomicAdd(&sums[tid], (double)s);
        atomicAdd(&sums[64 + tid], (double)qq);
    }
}

// ---- fused BN-finalize + BN-apply + dropout (threefry, XOR fold) + ReLU ----
__global__ __launch_bounds__(256) void k_bn_drop_relu(float* __restrict__ out,
                                                      const double* __restrict__ sums,
                                                      const float* __restrict__ gamma,
                                                      const float* __restrict__ beta) {
    __shared__ float ls_sc[64], ls_sh[64];
    const int tid = threadIdx.x;
    if (tid < 64) {
        const double mean = sums[tid] / (double)N;
        const double var  = sums[64 + tid] / (double)N - mean * mean;
        const float rstd  = (float)(1.0 / sqrt(var + (double)EPS));
        const float sc = gamma[tid] * rstd;
        ls_sc[tid] = sc;
        ls_sh[tid] = beta[tid] - (float)mean * sc;
    }
    __syncthreads();
    const int base = (blockIdx.x * 256 + tid) * 2;    // grid covers N*D/2 threads
    uint32_t p0 = 0u, p1 = (uint32_t)base;
    threefry2x32_k42(p0, p1);
    const uint32_t bits0 = p0 ^ p1;
    uint32_t q0 = 0u, q1 = (uint32_t)(base + 1);
    threefry2x32_k42(q0, q1);
    const uint32_t bits1 = q0 ^ q1;
    const int c0 = base & 63;                          // even; c1 = c0+1
    float2 v = *reinterpret_cast<const float2*>(&out[base]);
    v.x = v.x * ls_sc[c0]     + ls_sh[c0];
    v.y = v.y * ls_sc[c0 + 1] + ls_sh[c0 + 1];
    const float u0 = __uint_as_float((bits0 >> 9) | 0x3F800000u) - 1.0f;
    const float u1 = __uint_as_float((bits1 >> 9) | 0x3F800000u) - 1.0f;
    v.x = (u0 < 0.9f) ? v.x * (1.0f / 0.9f) : 0.0f;
    v.y = (u1 < 0.9f) ? v.y * (1.0f / 0.9f) : 0.0f;
    v.x = fmaxf(v.x, 0.f);
    v.y = fmaxf(v.y, 0.f);
    *reinterpret_cast<float2*>(&out[base]) = v;
}

// ---------------------------------------------------------------------------
extern "C" void kernel_launch(void* const* d_in, const int* in_sizes, int n_in,
                              void* d_out, int out_size, void* d_ws, size_t ws_size,
                              hipStream_t stream) {
    const float*    x     = (const float*)d_in[0];
    const uint32_t* ei    = (const uint32_t*)d_in[1];
    const float*    W     = (const float*)d_in[2];
    const float*    b     = (const float*)d_in[3];
    const float*    gamma = (const float*)d_in[4];
    const float*    beta  = (const float*)d_in[5];
    float* out = (float*)d_out;

    uint32_t* hs      = (uint32_t*)d_ws;               // N*32 u32 (bf16 rows, 12.8 MB)
    float*    dinv    = (float*)(hs + (size_t)N * 32); // N f32
    double*   sums    = (double*)(dinv + N);           // 128 f64 (8-aligned) ← zero span start
    uint32_t* dh      = (uint32_t*)(sums + 128);       // 128 degree histogram
    uint32_t* dcur    = dh + 128;                      // 128 degree cursors
    uint32_t* bcnt    = dcur + 128;                    // 3125 bucket counts
    uint32_t* bptr    = bcnt + NBKT;                   // 3126
    uint32_t* bcur    = bptr + NBKT + 1;               // 3125
    uint32_t* rowptr  = bcur + NBKT;                   // N+1
    uint32_t* perm    = rowptr + N + 1;                // N
    uint32_t* edata   = perm + N;                      // E (bucket-sorted packed)
    uint32_t* csr     = edata + E;                     // E   (total ≈ 24.5 MB)

    const int nb256 = (N + 255) / 256;                 // 391
    const int nz = 256 + 128 + 128 + NBKT;             // sums+dh+dcur+bcnt

    k_zero<<<(nz + 255) / 256, 256, 0, stream>>>((uint32_t*)sums, nz);
    k_prep<<<1024, 256, 0, stream>>>(ei, bcnt);
    k_bscan<<<1, 1024, 0, stream>>>(bcnt, bptr, bcur);
    k_bsort<<<1024, 256, 0, stream>>>(ei, bcur, edata);
    k_csr<<<NBKT, 256, 0, stream>>>(edata, bptr, csr, rowptr, dinv, dh);
    k_dscan<<<1, 128, 0, stream>>>(dh, dcur);
    k_perm<<<nb256, 256, 0, stream>>>(rowptr, dcur, perm);
    k_gemm<<<nb256, 256, 0, stream>>>(x, W, dinv, hs);
    k_gather_bn<<<GGRID, 256, 0, stream>>>(hs, dinv, rowptr, csr, perm, b, out, sums);
    k_bn_drop_relu<<<(N * D) / 512, 256, 0, stream>>>(out, sums, gamma, beta);
}

// Round 12
// 246.923 us; speedup vs baseline: 1.8518x; 1.8518x over previous
//
#include <hip/hip_runtime.h>
#include <cstdint>

static constexpr int N = 100000;
static constexpr int D = 64;
static constexpr int E = 1250000;
static constexpr int NBKT1 = 98;               // coarse buckets (dst>>10)
static constexpr int NBLK1 = 256;              // pass-1 blocks
static constexpr int CH1 = (E + NBLK1 - 1) / NBLK1;   // 4883 edges/chunk
static constexpr int MTOT = NBKT1 * NBLK1;     // 25088 count-matrix entries
static constexpr int NQ = N / 32;              // 3125 gather node-groups of 32
static constexpr int GGRID = 1563;             // gather grid: 2 balanced iters
static constexpr float EPS = 1e-5f;

// ---------------- threefry2x32, 20 rounds, key = (0, 42) --------------------
__device__ __forceinline__ uint32_t rotl32(uint32_t x, int r) {
    return (x << r) | (x >> (32 - r));
}

__device__ __forceinline__ void threefry2x32_k42(uint32_t& x0, uint32_t& x1) {
    const uint32_t ks0 = 0u, ks1 = 42u, ks2 = 0x1BD11BDAu ^ 0u ^ 42u;
    x0 += ks0; x1 += ks1;
#define TF_R4(a,b,c,d) \
    x0 += x1; x1 = rotl32(x1,a); x1 ^= x0; \
    x0 += x1; x1 = rotl32(x1,b); x1 ^= x0; \
    x0 += x1; x1 = rotl32(x1,c); x1 ^= x0; \
    x0 += x1; x1 = rotl32(x1,d); x1 ^= x0;
    TF_R4(13,15,26,6);  x0 += ks1; x1 += ks2 + 1u;
    TF_R4(17,29,16,24); x0 += ks2; x1 += ks0 + 2u;
    TF_R4(13,15,26,6);  x0 += ks0; x1 += ks1 + 3u;
    TF_R4(17,29,16,24); x0 += ks1; x1 += ks2 + 4u;
    TF_R4(13,15,26,6);  x0 += ks2; x1 += ks0 + 5u;
#undef TF_R4
}

// ---------------- bf16 helpers ---------------------------------------------
__device__ __forceinline__ uint32_t f2bf(float f) {          // RNE
    const uint32_t u = __float_as_uint(f);
    return (u + 0x7FFFu + ((u >> 16) & 1u)) >> 16;
}
__device__ __forceinline__ float bfl(uint32_t u) { return __uint_as_float(u << 16); }
__device__ __forceinline__ float bfh(uint32_t u) { return __uint_as_float(u & 0xFFFF0000u); }

__device__ __forceinline__ int load_idx(const uint32_t* raw, bool is64, int i) {
    return (int)(is64 ? raw[2u * (uint32_t)i] : raw[(uint32_t)i]);
}

// per-block int64 detection (first 256 odd words; broadcast reads, cheap)
__device__ __forceinline__ bool detect64(const uint32_t* raw) {
    __shared__ int s_is64;
    if (threadIdx.x < 64) {
        bool ok = true;
        #pragma unroll
        for (int k = 0; k < 4; ++k)
            ok &= (raw[(threadIdx.x * 4 + k) * 2 + 1] == 0u);
        const unsigned long long m = __ballot(ok);
        if (threadIdx.x == 0) s_is64 = (m == ~0ULL) ? 1 : 0;
    }
    __syncthreads();
    return s_is64 != 0;
}

// ------- zero sums + dh + dcur (512 u32) -----------------------------------
__global__ __launch_bounds__(256) void k_zero(uint32_t* __restrict__ z, int n32) {
    const int i = blockIdx.x * 256 + threadIdx.x;
    if (i < n32) z[i] = 0u;
}

// ------- pass-1a: per-(block,bucket) histogram of dst>>10 ------------------
__global__ __launch_bounds__(256) void k_hist1(const uint32_t* __restrict__ raw,
                                               uint32_t* __restrict__ cntM) {
    const bool is64 = detect64(raw);
    __shared__ uint32_t lh[NBKT1];
    if (threadIdx.x < NBKT1) lh[threadIdx.x] = 0u;
    __syncthreads();
    const int e0 = blockIdx.x * CH1;
    const int e1 = min(E, e0 + CH1);
    for (int e = e0 + (int)threadIdx.x; e < e1; e += 256) {
        const uint32_t d = (uint32_t)load_idx(raw, is64, E + e);
        atomicAdd(&lh[d >> 10], 1u);
    }
    __syncthreads();
    if (threadIdx.x < NBKT1)
        cntM[threadIdx.x * NBLK1 + blockIdx.x] = lh[threadIdx.x];   // bucket-major
}

// ------- pass-1b: scan 25088-entry count matrix → offsets + bptr -----------
__global__ __launch_bounds__(1024) void k_mscan(uint32_t* __restrict__ cntM,
                                                uint32_t* __restrict__ bptr) {
    __shared__ uint32_t ls[1024];
    const int t = threadIdx.x;
    const int per = (MTOT + 1023) / 1024;        // 25
    uint32_t loc[25];
    uint32_t s = 0;
    const int base = t * per;
    #pragma unroll
    for (int k = 0; k < 25; ++k) {
        const int i = base + k;
        const uint32_t v = (i < MTOT) ? cntM[i] : 0u;
        loc[k] = s; s += v;
    }
    ls[t] = s;
    __syncthreads();
    for (int off = 1; off < 1024; off <<= 1) {
        const uint32_t u = (t >= off) ? ls[t - off] : 0u;
        __syncthreads();
        ls[t] += u;
        __syncthreads();
    }
    const uint32_t pre = ls[t] - s;              // exclusive thread prefix
    #pragma unroll
    for (int k = 0; k < 25; ++k) {
        const int i = base + k;
        if (i < MTOT) {
            const uint32_t ex = pre + loc[k];
            cntM[i] = ex;
            if ((i & (NBLK1 - 1)) == 0) bptr[i / NBLK1] = ex;   // bucket start
        }
    }
    if (t == 1023) bptr[NBKT1] = (uint32_t)E;
}

// ------- pass-1c: LDS counting-sort chunk by bucket, flush contiguous runs --
__global__ __launch_bounds__(256) void k_flush1(const uint32_t* __restrict__ raw,
                                                const uint32_t* __restrict__ cntM,
                                                uint32_t* __restrict__ edata) {
    const bool is64 = detect64(raw);
    __shared__ uint32_t spk[CH1 + 64];
    __shared__ uint8_t  sbk[CH1 + 64];
    __shared__ uint32_t lcnt[NBKT1], lofs[NBKT1], lcur[NBKT1], gofs[NBKT1];
    const int t = threadIdx.x;
    if (t < NBKT1) {
        lcnt[t] = 0u;
        gofs[t] = cntM[t * NBLK1 + blockIdx.x];  // scanned global offset
    }
    __syncthreads();
    const int e0 = blockIdx.x * CH1;
    const int e1 = min(E, e0 + CH1);
    for (int e = e0 + t; e < e1; e += 256) {
        const uint32_t d = (uint32_t)load_idx(raw, is64, E + e);
        atomicAdd(&lcnt[d >> 10], 1u);
    }
    __syncthreads();
    if (t == 0) {
        uint32_t run = 0;
        for (int b2 = 0; b2 < NBKT1; ++b2) { lofs[b2] = run; run += lcnt[b2]; }
    }
    __syncthreads();
    if (t < NBKT1) lcur[t] = lofs[t];
    __syncthreads();
    for (int e = e0 + t; e < e1; e += 256) {
        const uint32_t s = (uint32_t)load_idx(raw, is64, e);
        const uint32_t d = (uint32_t)load_idx(raw, is64, E + e);
        const uint32_t b2 = d >> 10;
        const uint32_t p = atomicAdd(&lcur[b2], 1u);
        spk[p] = (s << 10) | (d & 1023u);        // src<2^17 → fits 27 bits
        sbk[p] = (uint8_t)b2;
    }
    __syncthreads();
    const int n = e1 - e0;
    for (int i = t; i < n; i += 256) {           // runs → coalesced-ish writes
        const uint32_t b2 = sbk[i];
        edata[gofs[b2] + ((uint32_t)i - lofs[b2])] = spk[i];
    }
}

// ------- pass-2: per-bucket CSR build, all global writes coalesced ---------
__global__ __launch_bounds__(1024) void k_csr2(const uint32_t* __restrict__ edata,
                                               const uint32_t* __restrict__ bptr,
                                               uint32_t* __restrict__ csr,
                                               uint32_t* __restrict__ rowptr,
                                               float* __restrict__ dinv,
                                               uint32_t* __restrict__ dh) {
    __shared__ uint32_t lh[1024], lsc[1024];
    __shared__ uint32_t lout[16384];             // 64 KB staging
    __shared__ uint32_t dhist[128];
    const int b = blockIdx.x, t = threadIdx.x;
    const uint32_t base = bptr[b];
    const uint32_t cnt  = bptr[b + 1] - base;
    lh[t] = 0u;
    if (t < 128) dhist[t] = 0u;
    __syncthreads();
    for (uint32_t i = t; i < cnt; i += 1024)
        atomicAdd(&lh[edata[base + i] & 1023u], 1u);
    __syncthreads();
    const uint32_t v = lh[t];
    lsc[t] = v;
    __syncthreads();
    for (int off = 1; off < 1024; off <<= 1) {
        const uint32_t u = (t >= off) ? lsc[t - off] : 0u;
        __syncthreads();
        lsc[t] += u;
        __syncthreads();
    }
    const uint32_t ex = lsc[t] - v;              // exclusive local offset
    const int node = b * 1024 + t;
    if (node < N) {
        rowptr[node] = base + ex;
        dinv[node] = rsqrtf((float)(v + 1u));
        atomicAdd(&dhist[min(v, 127u)], 1u);
    }
    if (b == 0 && t == 0) rowptr[N] = (uint32_t)E;
    __syncthreads();
    lh[t] = ex;                                  // reuse as cursor
    __syncthreads();
    for (uint32_t i = t; i < cnt; i += 1024) {
        const uint32_t pk = edata[base + i];
        const uint32_t p = atomicAdd(&lh[pk & 1023u], 1u);
        if (p < 16384u) lout[p] = pk >> 10;
        else            csr[base + p] = pk >> 10;        // overflow guard (never expected)
    }
    __syncthreads();
    const uint32_t m = min(cnt, 16384u);
    for (uint32_t i = t; i < m; i += 1024) csr[base + i] = lout[i];  // coalesced
    if (t < 128 && dhist[t] != 0u) atomicAdd(&dh[t], dhist[t]);
}

// ------- scan degree histogram dh[128] → dcur ------------------------------
__global__ __launch_bounds__(128) void k_dscan(const uint32_t* __restrict__ dh,
                                               uint32_t* __restrict__ dcur) {
    __shared__ uint32_t ls[128];
    const int t = threadIdx.x;
    const uint32_t hv = dh[t];
    ls[t] = hv;
    __syncthreads();
    for (int off = 1; off < 128; off <<= 1) {
        const uint32_t u = (t >= off) ? ls[t - off] : 0u;
        __syncthreads();
        ls[t] += u;
        __syncthreads();
    }
    dcur[t] = ls[t] - hv;                        // exclusive bucket start
}

// ------- counting-sort nodes by degree → perm (LDS-aggregated) -------------
__global__ __launch_bounds__(256) void k_perm(const uint32_t* __restrict__ rowptr,
                                              uint32_t* __restrict__ dcur,
                                              uint32_t* __restrict__ perm) {
    __shared__ uint32_t lcnt[128], lbase[128];
    const int tid = threadIdx.x;
    if (tid < 128) lcnt[tid] = 0u;
    __syncthreads();
    const int i = blockIdx.x * 256 + tid;
    int d = 0; uint32_t lrank = 0;
    if (i < N) {
        d = (int)min(rowptr[i + 1] - rowptr[i], 127u);
        lrank = atomicAdd(&lcnt[d], 1u);
    }
    __syncthreads();
    if (tid < 128 && lcnt[tid] != 0u) lbase[tid] = atomicAdd(&dcur[tid], lcnt[tid]);
    __syncthreads();
    if (i < N) perm[lbase[d] + lrank] = (uint32_t)i;
}

// ------- hs = bf16( (x @ W) * dinv[row] )  — dinv folded into GEMM ---------
__global__ __launch_bounds__(256) void k_gemm(const float* __restrict__ x,
                                              const float* __restrict__ W,
                                              const float* __restrict__ dinv,
                                              uint32_t* __restrict__ hs) {  // packed 2×bf16
    __shared__ float Ws[64 * 64];
    const int tid = threadIdx.x;
    #pragma unroll
    for (int i = 0; i < 4; ++i) {
        const int off = tid * 4 + i * 1024;
        *reinterpret_cast<float4*>(&Ws[off]) =
            *reinterpret_cast<const float4*>(&W[off]);
    }
    __syncthreads();
    const int row = blockIdx.x * 256 + tid;
    if (row >= N) return;
    const float* xr = x + (size_t)row * 64;
    float4 acc[16];
    #pragma unroll
    for (int i = 0; i < 16; ++i) acc[i] = make_float4(0.f, 0.f, 0.f, 0.f);
    for (int k = 0; k < 64; k += 4) {
        const float4 xv = *reinterpret_cast<const float4*>(xr + k);
        const float xs[4] = {xv.x, xv.y, xv.z, xv.w};
        #pragma unroll
        for (int kk = 0; kk < 4; ++kk) {
            const float s = xs[kk];
            const float4* wr = reinterpret_cast<const float4*>(&Ws[(k + kk) * 64]);
            #pragma unroll
            for (int d4 = 0; d4 < 16; ++d4) {
                const float4 w = wr[d4];
                acc[d4].x += s * w.x; acc[d4].y += s * w.y;
                acc[d4].z += s * w.z; acc[d4].w += s * w.w;
            }
        }
    }
    const float sc = dinv[row];
    uint32_t pack[32];
    #pragma unroll
    for (int i = 0; i < 16; ++i) {
        pack[2 * i]     = f2bf(acc[i].x * sc) | (f2bf(acc[i].y * sc) << 16);
        pack[2 * i + 1] = f2bf(acc[i].z * sc) | (f2bf(acc[i].w * sc) << 16);
    }
    uint4* hr = reinterpret_cast<uint4*>(hs + (size_t)row * 32);
    #pragma unroll
    for (int i = 0; i < 8; ++i) hr[i] = reinterpret_cast<const uint4*>(pack)[i];
}

// ---- gather: 8-lane group/dst, depth-8 batches, degree-sorted, fused BN ---
__global__ __launch_bounds__(256) void k_gather_bn(const uint32_t* __restrict__ hsu,
                                                   const float* __restrict__ dinv,
                                                   const uint32_t* __restrict__ rowptr,
                                                   const uint32_t* __restrict__ csr,
                                                   const uint32_t* __restrict__ perm,
                                                   const float* __restrict__ b,
                                                   float* __restrict__ out,
                                                   double* __restrict__ sums) {
    const int tid = threadIdx.x;
    const int grp = tid >> 3;            // 0..31: one dst node per 8-lane group
    const int sub = tid & 7;             // dims sub*8 .. sub*8+7
    float bb[8];
    {
        const float4 b0 = *reinterpret_cast<const float4*>(&b[sub * 8]);
        const float4 b1 = *reinterpret_cast<const float4*>(&b[sub * 8 + 4]);
        bb[0] = b0.x; bb[1] = b0.y; bb[2] = b0.z; bb[3] = b0.w;
        bb[4] = b1.x; bb[5] = b1.y; bb[6] = b1.z; bb[7] = b1.w;
    }
    float regS[8], regQ[8];
    #pragma unroll
    for (int k = 0; k < 8; ++k) { regS[k] = 0.f; regQ[k] = 0.f; }

    for (int q = blockIdx.x; q < NQ; q += GGRID) {       // ≤2 balanced iters
        const int d = (int)perm[q * 32 + grp];
        const uint32_t beg = rowptr[d], end = rowptr[d + 1];
        float a[8];
        {
            const uint4 sv = *reinterpret_cast<const uint4*>(&hsu[(size_t)d * 32 + sub * 4]);
            a[0] = bfl(sv.x); a[1] = bfh(sv.x); a[2] = bfl(sv.y); a[3] = bfh(sv.y);
            a[4] = bfl(sv.z); a[5] = bfh(sv.z); a[6] = bfl(sv.w); a[7] = bfh(sv.w);
        }
        uint32_t j = beg;
        while (j + 8 <= end) {                           // depth-8 batches
            const uint32_t sj = csr[j + (uint32_t)sub];  // 8 lanes: 8 edge ids
            uint4 v[8];
            #pragma unroll
            for (int k = 0; k < 8; ++k) {
                const int s = __shfl((int)sj, k, 8);     // group-local broadcast
                v[k] = *reinterpret_cast<const uint4*>(&hsu[(size_t)s * 32 + sub * 4]);
            }
            #pragma unroll
            for (int k = 0; k < 8; ++k) {
                a[0] += bfl(v[k].x); a[1] += bfh(v[k].x);
                a[2] += bfl(v[k].y); a[3] += bfh(v[k].y);
                a[4] += bfl(v[k].z); a[5] += bfh(v[k].z);
                a[6] += bfl(v[k].w); a[7] += bfh(v[k].w);
            }
            j += 8;
        }
        if (j < end) {                                   // tail < 8
            const uint32_t sj = (j + (uint32_t)sub < end) ? csr[j + (uint32_t)sub] : 0u;
            const int r = (int)(end - j);
            for (int k = 0; k < r; ++k) {
                const int s = __shfl((int)sj, k, 8);
                const uint4 vv = *reinterpret_cast<const uint4*>(&hsu[(size_t)s * 32 + sub * 4]);
                a[0] += bfl(vv.x); a[1] += bfh(vv.x);
                a[2] += bfl(vv.y); a[3] += bfh(vv.y);
                a[4] += bfl(vv.z); a[5] += bfh(vv.z);
                a[6] += bfl(vv.w); a[7] += bfh(vv.w);
            }
        }
        const float dd = dinv[d];
        float o[8];
        #pragma unroll
        for (int k = 0; k < 8; ++k) {
            o[k] = a[k] * dd + bb[k];
            regS[k] += o[k]; regQ[k] += o[k] * o[k];
        }
        const float4 o0 = make_float4(o[0], o[1], o[2], o[3]);
        const float4 o1 = make_float4(o[4], o[5], o[6], o[7]);
        *reinterpret_cast<float4*>(&out[(size_t)d * 64 + sub * 8])     = o0;
        *reinterpret_cast<float4*>(&out[(size_t)d * 64 + sub * 8 + 4]) = o1;
    }
    __shared__ float lsS[32][64], lsQ[32][64];
    #pragma unroll
    for (int k = 0; k < 8; ++k) {
        lsS[grp][sub * 8 + k] = regS[k];
        lsQ[grp][sub * 8 + k] = regQ[k];
    }
    __syncthreads();
    if (tid < 64) {
        float s = 0.f, qq = 0.f;
        #pragma unroll
        for (int g2 = 0; g2 < 32; ++g2) { s += lsS[g2][tid]; qq += lsQ[g2][tid]; }
        atomicAdd(&sums[tid], (double)s);
        atomicAdd(&sums[64 + tid], (double)qq);
    }
}

// ---- fused BN-finalize + BN-apply + dropout (threefry, XOR fold) + ReLU ----
__global__ __launch_bounds__(256) void k_bn_drop_relu(float* __restrict__ out,
                                                      const double* __restrict__ sums,
                                                      const float* __restrict__ gamma,
                                                      const float* __restrict__ beta) {
    __shared__ float ls_sc[64], ls_sh[64];
    const int tid = threadIdx.x;
    if (tid < 64) {
        const double mean = sums[tid] / (double)N;
        const double var  = sums[64 + tid] / (double)N - mean * mean;
        const float rstd  = (float)(1.0 / sqrt(var + (double)EPS));
        const float sc = gamma[tid] * rstd;
        ls_sc[tid] = sc;
        ls_sh[tid] = beta[tid] - (float)mean * sc;
    }
    __syncthreads();
    const int base = (blockIdx.x * 256 + tid) * 2;    // grid covers N*D/2 threads
    uint32_t p0 = 0u, p1 = (uint32_t)base;
    threefry2x32_k42(p0, p1);
    const uint32_t bits0 = p0 ^ p1;
    uint32_t q0 = 0u, q1 = (uint32_t)(base + 1);
    threefry2x32_k42(q0, q1);
    const uint32_t bits1 = q0 ^ q1;
    const int c0 = base & 63;                          // even; c1 = c0+1
    float2 v = *reinterpret_cast<const float2*>(&out[base]);
    v.x = v.x * ls_sc[c0]     + ls_sh[c0];
    v.y = v.y * ls_sc[c0 + 1] + ls_sh[c0 + 1];
    const float u0 = __uint_as_float((bits0 >> 9) | 0x3F800000u) - 1.0f;
    const float u1 = __uint_as_float((bits1 >> 9) | 0x3F800000u) - 1.0f;
    v.x = (u0 < 0.9f) ? v.x * (1.0f / 0.9f) : 0.0f;
    v.y = (u1 < 0.9f) ? v.y * (1.0f / 0.9f) : 0.0f;
    v.x = fmaxf(v.x, 0.f);
    v.y = fmaxf(v.y, 0.f);
    *reinterpret_cast<float2*>(&out[base]) = v;
}

// ---------------------------------------------------------------------------
extern "C" void kernel_launch(void* const* d_in, const int* in_sizes, int n_in,
                              void* d_out, int out_size, void* d_ws, size_t ws_size,
                              hipStream_t stream) {
    const float*    x     = (const float*)d_in[0];
    const uint32_t* ei    = (const uint32_t*)d_in[1];
    const float*    W     = (const float*)d_in[2];
    const float*    b     = (const float*)d_in[3];
    const float*    gamma = (const float*)d_in[4];
    const float*    beta  = (const float*)d_in[5];
    float* out = (float*)d_out;

    uint32_t* hs      = (uint32_t*)d_ws;               // N*32 u32 (bf16 rows, 12.8 MB)
    float*    dinv    = (float*)(hs + (size_t)N * 32); // N f32
    double*   sums    = (double*)(dinv + N);           // 128 f64 (8-aligned) ← zero span
    uint32_t* dh      = (uint32_t*)(sums + 128);       // 128 degree histogram
    uint32_t* dcur    = dh + 128;                      // 128 degree cursors
    uint32_t* bptr    = dcur + 128;                    // NBKT1+1 = 99
    uint32_t* cntM    = bptr + NBKT1 + 1;              // 25088 count matrix
    uint32_t* rowptr  = cntM + MTOT;                   // N+1
    uint32_t* perm    = rowptr + N + 1;                // N
    uint32_t* edata   = perm + N;                      // E (bucket-sorted packed)
    uint32_t* csr     = edata + E;                     // E   (total ≈ 24.5 MB)

    const int nb256 = (N + 255) / 256;                 // 391
    const int nz = 256 + 128 + 128;                    // sums+dh+dcur

    k_zero<<<2, 256, 0, stream>>>((uint32_t*)sums, nz);
    k_hist1<<<NBLK1, 256, 0, stream>>>(ei, cntM);
    k_mscan<<<1, 1024, 0, stream>>>(cntM, bptr);
    k_flush1<<<NBLK1, 256, 0, stream>>>(ei, cntM, edata);
    k_csr2<<<NBKT1, 1024, 0, stream>>>(edata, bptr, csr, rowptr, dinv, dh);
    k_dscan<<<1, 128, 0, stream>>>(dh, dcur);
    k_perm<<<nb256, 256, 0, stream>>>(rowptr, dcur, perm);
    k_gemm<<<nb256, 256, 0, stream>>>(x, W, dinv, hs);
    k_gather_bn<<<GGRID, 256, 0, stream>>>(hs, dinv, rowptr, csr, perm, b, out, sums);
    k_bn_drop_relu<<<(N * D) / 512, 256, 0, stream>>>(out, sums, gamma, beta);
}

// Round 13
// 242.750 us; speedup vs baseline: 1.8836x; 1.0172x over previous
//
#include <hip/hip_runtime.h>
#include <cstdint>

static constexpr int N = 100000;
static constexpr int D = 64;
static constexpr int E = 1250000;
static constexpr int NBKT1 = 98;               // coarse buckets (dst>>10)
static constexpr int NBLK1 = 256;              // pass-1 blocks
static constexpr int CH1 = (E + NBLK1 - 1) / NBLK1;   // 4883 edges/chunk
static constexpr int MTOT = NBKT1 * NBLK1;     // 25088 count-matrix entries
static constexpr int NQ = N / 32;              // 3125 gather node-groups of 32
static constexpr int GGRID = (NQ + 1) / 2;     // 1563: light+heavy pairing
static constexpr float EPS = 1e-5f;

// ---------------- threefry2x32, 20 rounds, key = (0, 42) --------------------
__device__ __forceinline__ uint32_t rotl32(uint32_t x, int r) {
    return (x << r) | (x >> (32 - r));
}

__device__ __forceinline__ void threefry2x32_k42(uint32_t& x0, uint32_t& x1) {
    const uint32_t ks0 = 0u, ks1 = 42u, ks2 = 0x1BD11BDAu ^ 0u ^ 42u;
    x0 += ks0; x1 += ks1;
#define TF_R4(a,b,c,d) \
    x0 += x1; x1 = rotl32(x1,a); x1 ^= x0; \
    x0 += x1; x1 = rotl32(x1,b); x1 ^= x0; \
    x0 += x1; x1 = rotl32(x1,c); x1 ^= x0; \
    x0 += x1; x1 = rotl32(x1,d); x1 ^= x0;
    TF_R4(13,15,26,6);  x0 += ks1; x1 += ks2 + 1u;
    TF_R4(17,29,16,24); x0 += ks2; x1 += ks0 + 2u;
    TF_R4(13,15,26,6);  x0 += ks0; x1 += ks1 + 3u;
    TF_R4(17,29,16,24); x0 += ks1; x1 += ks2 + 4u;
    TF_R4(13,15,26,6);  x0 += ks2; x1 += ks0 + 5u;
#undef TF_R4
}

// ---------------- bf16 helpers ---------------------------------------------
__device__ __forceinline__ uint32_t f2bf(float f) {          // RNE
    const uint32_t u = __float_as_uint(f);
    return (u + 0x7FFFu + ((u >> 16) & 1u)) >> 16;
}
__device__ __forceinline__ float bfl(uint32_t u) { return __uint_as_float(u << 16); }
__device__ __forceinline__ float bfh(uint32_t u) { return __uint_as_float(u & 0xFFFF0000u); }

__device__ __forceinline__ int load_idx(const uint32_t* raw, bool is64, int i) {
    return (int)(is64 ? raw[2u * (uint32_t)i] : raw[(uint32_t)i]);
}

// per-block int64 detection (first 256 odd words; broadcast reads, cheap)
__device__ __forceinline__ bool detect64(const uint32_t* raw) {
    __shared__ int s_is64;
    if (threadIdx.x < 64) {
        bool ok = true;
        #pragma unroll
        for (int k = 0; k < 4; ++k)
            ok &= (raw[(threadIdx.x * 4 + k) * 2 + 1] == 0u);
        const unsigned long long m = __ballot(ok);
        if (threadIdx.x == 0) s_is64 = (m == ~0ULL) ? 1 : 0;
    }
    __syncthreads();
    return s_is64 != 0;
}

// ------- pass-1a: per-(block,bucket) histogram of dst>>10 ------------------
__global__ __launch_bounds__(256) void k_hist1(const uint32_t* __restrict__ raw,
                                               uint32_t* __restrict__ cntM) {
    const bool is64 = detect64(raw);
    __shared__ uint32_t lh[NBKT1];
    if (threadIdx.x < NBKT1) lh[threadIdx.x] = 0u;
    __syncthreads();
    const int e0 = blockIdx.x * CH1;
    const int e1 = min(E, e0 + CH1);
    for (int e = e0 + (int)threadIdx.x; e < e1; e += 256) {
        const uint32_t d = (uint32_t)load_idx(raw, is64, E + e);
        atomicAdd(&lh[d >> 10], 1u);
    }
    __syncthreads();
    if (threadIdx.x < NBKT1)
        cntM[threadIdx.x * NBLK1 + blockIdx.x] = lh[threadIdx.x];   // bucket-major
}

// ------- pass-1b: scan count matrix → offsets + bptr; zero sums/dh ---------
__global__ __launch_bounds__(1024) void k_mscan(uint32_t* __restrict__ cntM,
                                                uint32_t* __restrict__ bptr,
                                                uint32_t* __restrict__ zero_span) {
    if (threadIdx.x < 256) zero_span[threadIdx.x] = 0u;   // sums(128 f32) + dh(128)
    __shared__ uint32_t ls[1024];
    const int t = threadIdx.x;
    const int per = (MTOT + 1023) / 1024;        // 25
    uint32_t loc[25];
    uint32_t s = 0;
    const int base = t * per;
    #pragma unroll
    for (int k = 0; k < 25; ++k) {
        const int i = base + k;
        const uint32_t v = (i < MTOT) ? cntM[i] : 0u;
        loc[k] = s; s += v;
    }
    ls[t] = s;
    __syncthreads();
    for (int off = 1; off < 1024; off <<= 1) {
        const uint32_t u = (t >= off) ? ls[t - off] : 0u;
        __syncthreads();
        ls[t] += u;
        __syncthreads();
    }
    const uint32_t pre = ls[t] - s;              // exclusive thread prefix
    #pragma unroll
    for (int k = 0; k < 25; ++k) {
        const int i = base + k;
        if (i < MTOT) {
            const uint32_t ex = pre + loc[k];
            cntM[i] = ex;
            if ((i & (NBLK1 - 1)) == 0) bptr[i / NBLK1] = ex;   // bucket start
        }
    }
    if (t == 1023) bptr[NBKT1] = (uint32_t)E;
}

// ------- pass-1c: LDS counting-sort chunk by bucket, flush contiguous runs --
__global__ __launch_bounds__(256) void k_flush1(const uint32_t* __restrict__ raw,
                                                const uint32_t* __restrict__ cntM,
                                                uint32_t* __restrict__ edata) {
    const bool is64 = detect64(raw);
    __shared__ uint32_t spk[CH1 + 64];
    __shared__ uint8_t  sbk[CH1 + 64];
    __shared__ uint32_t lcnt[NBKT1], lofs[NBKT1], lcur[NBKT1], gofs[NBKT1];
    const int t = threadIdx.x;
    if (t < NBKT1) {
        lcnt[t] = 0u;
        gofs[t] = cntM[t * NBLK1 + blockIdx.x];  // scanned global offset
    }
    __syncthreads();
    const int e0 = blockIdx.x * CH1;
    const int e1 = min(E, e0 + CH1);
    for (int e = e0 + t; e < e1; e += 256) {
        const uint32_t d = (uint32_t)load_idx(raw, is64, E + e);
        atomicAdd(&lcnt[d >> 10], 1u);
    }
    __syncthreads();
    if (t == 0) {
        uint32_t run = 0;
        for (int b2 = 0; b2 < NBKT1; ++b2) { lofs[b2] = run; run += lcnt[b2]; }
    }
    __syncthreads();
    if (t < NBKT1) lcur[t] = lofs[t];
    __syncthreads();
    for (int e = e0 + t; e < e1; e += 256) {
        const uint32_t s = (uint32_t)load_idx(raw, is64, e);
        const uint32_t d = (uint32_t)load_idx(raw, is64, E + e);
        const uint32_t b2 = d >> 10;
        const uint32_t p = atomicAdd(&lcur[b2], 1u);
        spk[p] = (s << 10) | (d & 1023u);        // src<2^17 → fits 27 bits
        sbk[p] = (uint8_t)b2;
    }
    __syncthreads();
    const int n = e1 - e0;
    for (int i = t; i < n; i += 256) {           // runs → coalesced-ish writes
        const uint32_t b2 = sbk[i];
        edata[gofs[b2] + ((uint32_t)i - lofs[b2])] = spk[i];
    }
}

// ------- pass-2: per-bucket CSR build, all global writes coalesced ---------
__global__ __launch_bounds__(1024) void k_csr2(const uint32_t* __restrict__ edata,
                                               const uint32_t* __restrict__ bptr,
                                               uint32_t* __restrict__ csr,
                                               uint32_t* __restrict__ rowptr,
                                               float* __restrict__ dinv,
                                               uint32_t* __restrict__ dh) {
    __shared__ uint32_t lh[1024], lsc[1024];
    __shared__ uint32_t lout[16384];             // 64 KB staging
    __shared__ uint32_t dhist[128];
    const int b = blockIdx.x, t = threadIdx.x;
    const uint32_t base = bptr[b];
    const uint32_t cnt  = bptr[b + 1] - base;
    lh[t] = 0u;
    if (t < 128) dhist[t] = 0u;
    __syncthreads();
    for (uint32_t i = t; i < cnt; i += 1024)
        atomicAdd(&lh[edata[base + i] & 1023u], 1u);
    __syncthreads();
    const uint32_t v = lh[t];
    lsc[t] = v;
    __syncthreads();
    for (int off = 1; off < 1024; off <<= 1) {
        const uint32_t u = (t >= off) ? lsc[t - off] : 0u;
        __syncthreads();
        lsc[t] += u;
        __syncthreads();
    }
    const uint32_t ex = lsc[t] - v;              // exclusive local offset
    const int node = b * 1024 + t;
    if (node < N) {
        rowptr[node] = base + ex;
        dinv[node] = rsqrtf((float)(v + 1u));
        atomicAdd(&dhist[min(v, 127u)], 1u);
    }
    if (b == 0 && t == 0) rowptr[N] = (uint32_t)E;
    __syncthreads();
    lh[t] = ex;                                  // reuse as cursor
    __syncthreads();
    for (uint32_t i = t; i < cnt; i += 1024) {
        const uint32_t pk = edata[base + i];
        const uint32_t p = atomicAdd(&lh[pk & 1023u], 1u);
        if (p < 16384u) lout[p] = pk >> 10;
        else            csr[base + p] = pk >> 10;        // overflow guard
    }
    __syncthreads();
    const uint32_t m = min(cnt, 16384u);
    for (uint32_t i = t; i < m; i += 1024) csr[base + i] = lout[i];  // coalesced
    if (t < 128 && dhist[t] != 0u) atomicAdd(&dh[t], dhist[t]);
}

// ------- scan degree histogram dh[128] → dcur ------------------------------
__global__ __launch_bounds__(128) void k_dscan(const uint32_t* __restrict__ dh,
                                               uint32_t* __restrict__ dcur) {
    __shared__ uint32_t ls[128];
    const int t = threadIdx.x;
    const uint32_t hv = dh[t];
    ls[t] = hv;
    __syncthreads();
    for (int off = 1; off < 128; off <<= 1) {
        const uint32_t u = (t >= off) ? ls[t - off] : 0u;
        __syncthreads();
        ls[t] += u;
        __syncthreads();
    }
    dcur[t] = ls[t] - hv;                        // exclusive bucket start
}

// ------- counting-sort nodes by degree → perm (LDS-aggregated) -------------
__global__ __launch_bounds__(256) void k_perm(const uint32_t* __restrict__ rowptr,
                                              uint32_t* __restrict__ dcur,
                                              uint32_t* __restrict__ perm) {
    __shared__ uint32_t lcnt[128], lbase[128];
    const int tid = threadIdx.x;
    if (tid < 128) lcnt[tid] = 0u;
    __syncthreads();
    const int i = blockIdx.x * 256 + tid;
    int d = 0; uint32_t lrank = 0;
    if (i < N) {
        d = (int)min(rowptr[i + 1] - rowptr[i], 127u);
        lrank = atomicAdd(&lcnt[d], 1u);
    }
    __syncthreads();
    if (tid < 128 && lcnt[tid] != 0u) lbase[tid] = atomicAdd(&dcur[tid], lcnt[tid]);
    __syncthreads();
    if (i < N) perm[lbase[d] + lrank] = (uint32_t)i;
}

// ------- hs = bf16( (x @ W) * dinv[row] )  — dinv folded into GEMM ---------
__global__ __launch_bounds__(256) void k_gemm(const float* __restrict__ x,
                                              const float* __restrict__ W,
                                              const float* __restrict__ dinv,
                                              uint32_t* __restrict__ hs) {  // packed 2×bf16
    __shared__ float Ws[64 * 64];
    const int tid = threadIdx.x;
    #pragma unroll
    for (int i = 0; i < 4; ++i) {
        const int off = tid * 4 + i * 1024;
        *reinterpret_cast<float4*>(&Ws[off]) =
            *reinterpret_cast<const float4*>(&W[off]);
    }
    __syncthreads();
    const int row = blockIdx.x * 256 + tid;
    if (row >= N) return;
    const float* xr = x + (size_t)row * 64;
    float4 acc[16];
    #pragma unroll
    for (int i = 0; i < 16; ++i) acc[i] = make_float4(0.f, 0.f, 0.f, 0.f);
    for (int k = 0; k < 64; k += 4) {
        const float4 xv = *reinterpret_cast<const float4*>(xr + k);
        const float xs[4] = {xv.x, xv.y, xv.z, xv.w};
        #pragma unroll
        for (int kk = 0; kk < 4; ++kk) {
            const float s = xs[kk];
            const float4* wr = reinterpret_cast<const float4*>(&Ws[(k + kk) * 64]);
            #pragma unroll
            for (int d4 = 0; d4 < 16; ++d4) {
                const float4 w = wr[d4];
                acc[d4].x += s * w.x; acc[d4].y += s * w.y;
                acc[d4].z += s * w.z; acc[d4].w += s * w.w;
            }
        }
    }
    const float sc = dinv[row];
    uint32_t pack[32];
    #pragma unroll
    for (int i = 0; i < 16; ++i) {
        pack[2 * i]     = f2bf(acc[i].x * sc) | (f2bf(acc[i].y * sc) << 16);
        pack[2 * i + 1] = f2bf(acc[i].z * sc) | (f2bf(acc[i].w * sc) << 16);
    }
    uint4* hr = reinterpret_cast<uint4*>(hs + (size_t)row * 32);
    #pragma unroll
    for (int i = 0; i < 8; ++i) hr[i] = reinterpret_cast<const uint4*>(pack)[i];
}

// ---- gather: 8-lane group/dst, depth-8, light+heavy paired, fused BN ------
__global__ __launch_bounds__(256) void k_gather_bn(const uint32_t* __restrict__ hsu,
                                                   const float* __restrict__ dinv,
                                                   const uint32_t* __restrict__ rowptr,
                                                   const uint32_t* __restrict__ csr,
                                                   const uint32_t* __restrict__ perm,
                                                   const float* __restrict__ b,
                                                   float* __restrict__ out,
                                                   float* __restrict__ sums) {
    const int tid = threadIdx.x;
    const int grp = tid >> 3;            // 0..31: one dst node per 8-lane group
    const int sub = tid & 7;             // dims sub*8 .. sub*8+7
    float bb[8];
    {
        const float4 b0 = *reinterpret_cast<const float4*>(&b[sub * 8]);
        const float4 b1 = *reinterpret_cast<const float4*>(&b[sub * 8 + 4]);
        bb[0] = b0.x; bb[1] = b0.y; bb[2] = b0.z; bb[3] = b0.w;
        bb[4] = b1.x; bb[5] = b1.y; bb[6] = b1.z; bb[7] = b1.w;
    }
    float regS[8], regQ[8];
    #pragma unroll
    for (int k = 0; k < 8; ++k) { regS[k] = 0.f; regQ[k] = 0.f; }

    // pairing: block i handles perm-group i (light) and NQ-1-i (heavy)
    #pragma unroll
    for (int it = 0; it < 2; ++it) {
        const int q = it ? (NQ - 1 - (int)blockIdx.x) : (int)blockIdx.x;
        if (it && q <= (int)blockIdx.x) break;           // middle group once
        const int d = (int)perm[q * 32 + grp];
        const uint32_t beg = rowptr[d], end = rowptr[d + 1];
        float a[8];
        {
            const uint4 sv = *reinterpret_cast<const uint4*>(&hsu[(size_t)d * 32 + sub * 4]);
            a[0] = bfl(sv.x); a[1] = bfh(sv.x); a[2] = bfl(sv.y); a[3] = bfh(sv.y);
            a[4] = bfl(sv.z); a[5] = bfh(sv.z); a[6] = bfl(sv.w); a[7] = bfh(sv.w);
        }
        uint32_t j = beg;
        while (j + 8 <= end) {                           // depth-8 batches
            const uint32_t sj = csr[j + (uint32_t)sub];  // 8 lanes: 8 edge ids
            uint4 v[8];
            #pragma unroll
            for (int k = 0; k < 8; ++k) {
                const int s = __shfl((int)sj, k, 8);     // group-local broadcast
                v[k] = *reinterpret_cast<const uint4*>(&hsu[(size_t)s * 32 + sub * 4]);
            }
            #pragma unroll
            for (int k = 0; k < 8; ++k) {
                a[0] += bfl(v[k].x); a[1] += bfh(v[k].x);
                a[2] += bfl(v[k].y); a[3] += bfh(v[k].y);
                a[4] += bfl(v[k].z); a[5] += bfh(v[k].z);
                a[6] += bfl(v[k].w); a[7] += bfh(v[k].w);
            }
            j += 8;
        }
        if (j < end) {                                   // tail < 8
            const uint32_t sj = (j + (uint32_t)sub < end) ? csr[j + (uint32_t)sub] : 0u;
            const int r = (int)(end - j);
            for (int k = 0; k < r; ++k) {
                const int s = __shfl((int)sj, k, 8);
                const uint4 vv = *reinterpret_cast<const uint4*>(&hsu[(size_t)s * 32 + sub * 4]);
                a[0] += bfl(vv.x); a[1] += bfh(vv.x);
                a[2] += bfl(vv.y); a[3] += bfh(vv.y);
                a[4] += bfl(vv.z); a[5] += bfh(vv.z);
                a[6] += bfl(vv.w); a[7] += bfh(vv.w);
            }
        }
        const float dd = dinv[d];
        float o[8];
        #pragma unroll
        for (int k = 0; k < 8; ++k) {
            o[k] = a[k] * dd + bb[k];
            regS[k] += o[k]; regQ[k] += o[k] * o[k];
        }
        const float4 o0 = make_float4(o[0], o[1], o[2], o[3]);
        const float4 o1 = make_float4(o[4], o[5], o[6], o[7]);
        *reinterpret_cast<float4*>(&out[(size_t)d * 64 + sub * 8])     = o0;
        *reinterpret_cast<float4*>(&out[(size_t)d * 64 + sub * 8 + 4]) = o1;
    }
    __shared__ float lsS[32][64], lsQ[32][64];
    #pragma unroll
    for (int k = 0; k < 8; ++k) {
        lsS[grp][sub * 8 + k] = regS[k];
        lsQ[grp][sub * 8 + k] = regQ[k];
    }
    __syncthreads();
    if (tid < 64) {
        float s = 0.f, qq = 0.f;
        #pragma unroll
        for (int g2 = 0; g2 < 32; ++g2) { s += lsS[g2][tid]; qq += lsQ[g2][tid]; }
        atomicAdd(&sums[tid], s);
        atomicAdd(&sums[64 + tid], qq);
    }
}

// ---- fused BN-finalize + BN-apply + dropout (threefry, XOR fold) + ReLU ----
__global__ __launch_bounds__(256) void k_bn_drop_relu(float* __restrict__ out,
                                                      const float* __restrict__ sums,
                                                      const float* __restrict__ gamma,
                                                      const float* __restrict__ beta) {
    __shared__ float ls_sc[64], ls_sh[64];
    const int tid = threadIdx.x;
    if (tid < 64) {
        const float mean = sums[tid] * (1.0f / (float)N);
        const float var  = sums[64 + tid] * (1.0f / (float)N) - mean * mean;
        const float rstd = rsqrtf(var + EPS);
        const float sc = gamma[tid] * rstd;
        ls_sc[tid] = sc;
        ls_sh[tid] = beta[tid] - mean * sc;
    }
    __syncthreads();
    const int base = (blockIdx.x * 256 + tid) * 2;    // grid covers N*D/2 threads
    uint32_t p0 = 0u, p1 = (uint32_t)base;
    threefry2x32_k42(p0, p1);
    const uint32_t bits0 = p0 ^ p1;
    uint32_t q0 = 0u, q1 = (uint32_t)(base + 1);
    threefry2x32_k42(q0, q1);
    const uint32_t bits1 = q0 ^ q1;
    const int c0 = base & 63;                          // even; c1 = c0+1
    float2 v = *reinterpret_cast<const float2*>(&out[base]);
    v.x = v.x * ls_sc[c0]     + ls_sh[c0];
    v.y = v.y * ls_sc[c0 + 1] + ls_sh[c0 + 1];
    const float u0 = __uint_as_float((bits0 >> 9) | 0x3F800000u) - 1.0f;
    const float u1 = __uint_as_float((bits1 >> 9) | 0x3F800000u) - 1.0f;
    v.x = (u0 < 0.9f) ? v.x * (1.0f / 0.9f) : 0.0f;
    v.y = (u1 < 0.9f) ? v.y * (1.0f / 0.9f) : 0.0f;
    v.x = fmaxf(v.x, 0.f);
    v.y = fmaxf(v.y, 0.f);
    *reinterpret_cast<float2*>(&out[base]) = v;
}

// ---------------------------------------------------------------------------
extern "C" void kernel_launch(void* const* d_in, const int* in_sizes, int n_in,
                              void* d_out, int out_size, void* d_ws, size_t ws_size,
                              hipStream_t stream) {
    const float*    x     = (const float*)d_in[0];
    const uint32_t* ei    = (const uint32_t*)d_in[1];
    const float*    W     = (const float*)d_in[2];
    const float*    b     = (const float*)d_in[3];
    const float*    gamma = (const float*)d_in[4];
    const float*    beta  = (const float*)d_in[5];
    float* out = (float*)d_out;

    uint32_t* hs      = (uint32_t*)d_ws;               // N*32 u32 (bf16 rows, 12.8 MB)
    float*    dinv    = (float*)(hs + (size_t)N * 32); // N f32
    float*    sums    = (float*)(dinv + N);            // 128 f32 ← zero span (in mscan)
    uint32_t* dh      = (uint32_t*)(sums + 128);       // 128 degree histogram
    uint32_t* dcur    = dh + 128;                      // 128 degree cursors
    uint32_t* bptr    = dcur + 128;                    // NBKT1+1 = 99
    uint32_t* cntM    = bptr + NBKT1 + 1;              // 25088 count matrix
    uint32_t* rowptr  = cntM + MTOT;                   // N+1
    uint32_t* perm    = rowptr + N + 1;                // N
    uint32_t* edata   = perm + N;                      // E (bucket-sorted packed)
    uint32_t* csr     = edata + E;                     // E   (total ≈ 24.5 MB)

    const int nb256 = (N + 255) / 256;                 // 391

    k_hist1<<<NBLK1, 256, 0, stream>>>(ei, cntM);
    k_mscan<<<1, 1024, 0, stream>>>(cntM, bptr, (uint32_t*)sums);
    k_flush1<<<NBLK1, 256, 0, stream>>>(ei, cntM, edata);
    k_csr2<<<NBKT1, 1024, 0, stream>>>(edata, bptr, csr, rowptr, dinv, dh);
    k_dscan<<<1, 128, 0, stream>>>(dh, dcur);
    k_perm<<<nb256, 256, 0, stream>>>(rowptr, dcur, perm);
    k_gemm<<<nb256, 256, 0, stream>>>(x, W, dinv, hs);
    k_gather_bn<<<GGRID, 256, 0, stream>>>(hs, dinv, rowptr, csr, perm, b, out, sums);
    k_bn_drop_relu<<<(N * D) / 512, 256, 0, stream>>>(out, sums, gamma, beta);
}

// Round 14
// 241.605 us; speedup vs baseline: 1.8925x; 1.0047x over previous
//
#include <hip/hip_runtime.h>
#include <cstdint>

static constexpr int N = 100000;
static constexpr int D = 64;
static constexpr int E = 1250000;
static constexpr int NBKT1 = 98;               // coarse buckets (dst>>10)
static constexpr int NBLK1 = 256;              // pass-1 blocks
static constexpr int CH1 = (E + NBLK1 - 1) / NBLK1;   // 4883 edges/chunk
static constexpr int MTOT = NBKT1 * NBLK1;     // 25088 count-matrix entries
static constexpr int NQ = N / 32;              // 3125 gather node-groups of 32
static constexpr int GGRID = (NQ + 1) / 2;     // 1563: light+heavy pairing
static constexpr float EPS = 1e-5f;

// ---------------- threefry2x32, 20 rounds, key = (0, 42) --------------------
__device__ __forceinline__ uint32_t rotl32(uint32_t x, int r) {
    return (x << r) | (x >> (32 - r));
}

__device__ __forceinline__ void threefry2x32_k42(uint32_t& x0, uint32_t& x1) {
    const uint32_t ks0 = 0u, ks1 = 42u, ks2 = 0x1BD11BDAu ^ 0u ^ 42u;
    x0 += ks0; x1 += ks1;
#define TF_R4(a,b,c,d) \
    x0 += x1; x1 = rotl32(x1,a); x1 ^= x0; \
    x0 += x1; x1 = rotl32(x1,b); x1 ^= x0; \
    x0 += x1; x1 = rotl32(x1,c); x1 ^= x0; \
    x0 += x1; x1 = rotl32(x1,d); x1 ^= x0;
    TF_R4(13,15,26,6);  x0 += ks1; x1 += ks2 + 1u;
    TF_R4(17,29,16,24); x0 += ks2; x1 += ks0 + 2u;
    TF_R4(13,15,26,6);  x0 += ks0; x1 += ks1 + 3u;
    TF_R4(17,29,16,24); x0 += ks1; x1 += ks2 + 4u;
    TF_R4(13,15,26,6);  x0 += ks2; x1 += ks0 + 5u;
#undef TF_R4
}

// ---------------- bf16 helpers ---------------------------------------------
__device__ __forceinline__ uint32_t f2bf(float f) {          // RNE
    const uint32_t u = __float_as_uint(f);
    return (u + 0x7FFFu + ((u >> 16) & 1u)) >> 16;
}
__device__ __forceinline__ float bfl(uint32_t u) { return __uint_as_float(u << 16); }
__device__ __forceinline__ float bfh(uint32_t u) { return __uint_as_float(u & 0xFFFF0000u); }

__device__ __forceinline__ int load_idx(const uint32_t* raw, bool is64, int i) {
    return (int)(is64 ? raw[2u * (uint32_t)i] : raw[(uint32_t)i]);
}

// per-block int64 detection (first 256 odd words; broadcast reads, cheap)
__device__ __forceinline__ bool detect64(const uint32_t* raw) {
    __shared__ int s_is64;
    if (threadIdx.x < 64) {
        bool ok = true;
        #pragma unroll
        for (int k = 0; k < 4; ++k)
            ok &= (raw[(threadIdx.x * 4 + k) * 2 + 1] == 0u);
        const unsigned long long m = __ballot(ok);
        if (threadIdx.x == 0) s_is64 = (m == ~0ULL) ? 1 : 0;
    }
    __syncthreads();
    return s_is64 != 0;
}

// ------- pass-1a: per-(block,bucket) histogram of dst>>10 ------------------
__global__ __launch_bounds__(256) void k_hist1(const uint32_t* __restrict__ raw,
                                               uint32_t* __restrict__ cntM) {
    const bool is64 = detect64(raw);
    __shared__ uint32_t lh[NBKT1];
    if (threadIdx.x < NBKT1) lh[threadIdx.x] = 0u;
    __syncthreads();
    const int e0 = blockIdx.x * CH1;
    const int e1 = min(E, e0 + CH1);
    for (int e = e0 + (int)threadIdx.x; e < e1; e += 256) {
        const uint32_t d = (uint32_t)load_idx(raw, is64, E + e);
        atomicAdd(&lh[d >> 10], 1u);
    }
    __syncthreads();
    if (threadIdx.x < NBKT1)
        cntM[threadIdx.x * NBLK1 + blockIdx.x] = lh[threadIdx.x];   // bucket-major
}

// ------- pass-1b: scan count matrix → offsets + bptr; zero sums/dh ---------
__global__ __launch_bounds__(1024) void k_mscan(uint32_t* __restrict__ cntM,
                                                uint32_t* __restrict__ bptr,
                                                uint32_t* __restrict__ zero_span) {
    if (threadIdx.x < 256) zero_span[threadIdx.x] = 0u;   // sums(128 f32) + dh(128)
    __shared__ uint32_t ls[1024];
    const int t = threadIdx.x;
    const int per = (MTOT + 1023) / 1024;        // 25
    uint32_t loc[25];
    uint32_t s = 0;
    const int base = t * per;
    #pragma unroll
    for (int k = 0; k < 25; ++k) {
        const int i = base + k;
        const uint32_t v = (i < MTOT) ? cntM[i] : 0u;
        loc[k] = s; s += v;
    }
    ls[t] = s;
    __syncthreads();
    for (int off = 1; off < 1024; off <<= 1) {
        const uint32_t u = (t >= off) ? ls[t - off] : 0u;
        __syncthreads();
        ls[t] += u;
        __syncthreads();
    }
    const uint32_t pre = ls[t] - s;              // exclusive thread prefix
    #pragma unroll
    for (int k = 0; k < 25; ++k) {
        const int i = base + k;
        if (i < MTOT) {
            const uint32_t ex = pre + loc[k];
            cntM[i] = ex;
            if ((i & (NBLK1 - 1)) == 0) bptr[i / NBLK1] = ex;   // bucket start
        }
    }
    if (t == 1023) bptr[NBKT1] = (uint32_t)E;
}

// ------- pass-1c: LDS counting-sort chunk by bucket, flush contiguous runs --
__global__ __launch_bounds__(256) void k_flush1(const uint32_t* __restrict__ raw,
                                                const uint32_t* __restrict__ cntM,
                                                uint32_t* __restrict__ edata) {
    const bool is64 = detect64(raw);
    __shared__ uint32_t spk[CH1 + 64];
    __shared__ uint8_t  sbk[CH1 + 64];
    __shared__ uint32_t lcnt[NBKT1], lofs[NBKT1], lcur[NBKT1], gofs[NBKT1];
    const int t = threadIdx.x;
    if (t < NBKT1) {
        lcnt[t] = 0u;
        gofs[t] = cntM[t * NBLK1 + blockIdx.x];  // scanned global offset
    }
    __syncthreads();
    const int e0 = blockIdx.x * CH1;
    const int e1 = min(E, e0 + CH1);
    for (int e = e0 + t; e < e1; e += 256) {
        const uint32_t d = (uint32_t)load_idx(raw, is64, E + e);
        atomicAdd(&lcnt[d >> 10], 1u);
    }
    __syncthreads();
    if (t == 0) {
        uint32_t run = 0;
        for (int b2 = 0; b2 < NBKT1; ++b2) { lofs[b2] = run; run += lcnt[b2]; }
    }
    __syncthreads();
    if (t < NBKT1) lcur[t] = lofs[t];
    __syncthreads();
    for (int e = e0 + t; e < e1; e += 256) {
        const uint32_t s = (uint32_t)load_idx(raw, is64, e);
        const uint32_t d = (uint32_t)load_idx(raw, is64, E + e);
        const uint32_t b2 = d >> 10;
        const uint32_t p = atomicAdd(&lcur[b2], 1u);
        spk[p] = (s << 10) | (d & 1023u);        // src<2^17 → fits 27 bits
        sbk[p] = (uint8_t)b2;
    }
    __syncthreads();
    const int n = e1 - e0;
    for (int i = t; i < n; i += 256) {           // runs → coalesced-ish writes
        const uint32_t b2 = sbk[i];
        edata[gofs[b2] + ((uint32_t)i - lofs[b2])] = spk[i];
    }
}

// ------- pass-2: per-bucket CSR build, all global writes coalesced ---------
__global__ __launch_bounds__(1024) void k_csr2(const uint32_t* __restrict__ edata,
                                               const uint32_t* __restrict__ bptr,
                                               uint32_t* __restrict__ csr,
                                               uint32_t* __restrict__ rowptr,
                                               float* __restrict__ dinv,
                                               uint32_t* __restrict__ dh) {
    __shared__ uint32_t lh[1024], lsc[1024];
    __shared__ uint32_t lout[16384];             // 64 KB staging
    __shared__ uint32_t dhist[128];
    const int b = blockIdx.x, t = threadIdx.x;
    const uint32_t base = bptr[b];
    const uint32_t cnt  = bptr[b + 1] - base;
    lh[t] = 0u;
    if (t < 128) dhist[t] = 0u;
    __syncthreads();
    for (uint32_t i = t; i < cnt; i += 1024)
        atomicAdd(&lh[edata[base + i] & 1023u], 1u);
    __syncthreads();
    const uint32_t v = lh[t];
    lsc[t] = v;
    __syncthreads();
    for (int off = 1; off < 1024; off <<= 1) {
        const uint32_t u = (t >= off) ? lsc[t - off] : 0u;
        __syncthreads();
        lsc[t] += u;
        __syncthreads();
    }
    const uint32_t ex = lsc[t] - v;              // exclusive local offset
    const int node = b * 1024 + t;
    if (node < N) {
        rowptr[node] = base + ex;
        dinv[node] = rsqrtf((float)(v + 1u));
        atomicAdd(&dhist[min(v, 127u)], 1u);
    }
    if (b == 0 && t == 0) rowptr[N] = (uint32_t)E;
    __syncthreads();
    lh[t] = ex;                                  // reuse as cursor
    __syncthreads();
    for (uint32_t i = t; i < cnt; i += 1024) {
        const uint32_t pk = edata[base + i];
        const uint32_t p = atomicAdd(&lh[pk & 1023u], 1u);
        if (p < 16384u) lout[p] = pk >> 10;
        else            csr[base + p] = pk >> 10;        // overflow guard
    }
    __syncthreads();
    const uint32_t m = min(cnt, 16384u);
    for (uint32_t i = t; i < m; i += 1024) csr[base + i] = lout[i];  // coalesced
    if (t < 128 && dhist[t] != 0u) atomicAdd(&dh[t], dhist[t]);
}

// ------- scan degree histogram dh[128] → dcur ------------------------------
__global__ __launch_bounds__(128) void k_dscan(const uint32_t* __restrict__ dh,
                                               uint32_t* __restrict__ dcur) {
    __shared__ uint32_t ls[128];
    const int t = threadIdx.x;
    const uint32_t hv = dh[t];
    ls[t] = hv;
    __syncthreads();
    for (int off = 1; off < 128; off <<= 1) {
        const uint32_t u = (t >= off) ? ls[t - off] : 0u;
        __syncthreads();
        ls[t] += u;
        __syncthreads();
    }
    dcur[t] = ls[t] - hv;                        // exclusive bucket start
}

// ------- counting-sort nodes by degree → perm (LDS-aggregated) -------------
__global__ __launch_bounds__(256) void k_perm(const uint32_t* __restrict__ rowptr,
                                              uint32_t* __restrict__ dcur,
                                              uint32_t* __restrict__ perm) {
    __shared__ uint32_t lcnt[128], lbase[128];
    const int tid = threadIdx.x;
    if (tid < 128) lcnt[tid] = 0u;
    __syncthreads();
    const int i = blockIdx.x * 256 + tid;
    int d = 0; uint32_t lrank = 0;
    if (i < N) {
        d = (int)min(rowptr[i + 1] - rowptr[i], 127u);
        lrank = atomicAdd(&lcnt[d], 1u);
    }
    __syncthreads();
    if (tid < 128 && lcnt[tid] != 0u) lbase[tid] = atomicAdd(&dcur[tid], lcnt[tid]);
    __syncthreads();
    if (i < N) perm[lbase[d] + lrank] = (uint32_t)i;
}

// ------- hs = bf16( (x @ W) * dinv[row] )  — dinv folded into GEMM ---------
__global__ __launch_bounds__(256) void k_gemm(const float* __restrict__ x,
                                              const float* __restrict__ W,
                                              const float* __restrict__ dinv,
                                              uint32_t* __restrict__ hs) {  // packed 2×bf16
    __shared__ float Ws[64 * 64];
    const int tid = threadIdx.x;
    #pragma unroll
    for (int i = 0; i < 4; ++i) {
        const int off = tid * 4 + i * 1024;
        *reinterpret_cast<float4*>(&Ws[off]) =
            *reinterpret_cast<const float4*>(&W[off]);
    }
    __syncthreads();
    const int row = blockIdx.x * 256 + tid;
    if (row >= N) return;
    const float* xr = x + (size_t)row * 64;
    float4 acc[16];
    #pragma unroll
    for (int i = 0; i < 16; ++i) acc[i] = make_float4(0.f, 0.f, 0.f, 0.f);
    for (int k = 0; k < 64; k += 4) {
        const float4 xv = *reinterpret_cast<const float4*>(xr + k);
        const float xs[4] = {xv.x, xv.y, xv.z, xv.w};
        #pragma unroll
        for (int kk = 0; kk < 4; ++kk) {
            const float s = xs[kk];
            const float4* wr = reinterpret_cast<const float4*>(&Ws[(k + kk) * 64]);
            #pragma unroll
            for (int d4 = 0; d4 < 16; ++d4) {
                const float4 w = wr[d4];
                acc[d4].x += s * w.x; acc[d4].y += s * w.y;
                acc[d4].z += s * w.z; acc[d4].w += s * w.w;
            }
        }
    }
    const float sc = dinv[row];
    uint32_t pack[32];
    #pragma unroll
    for (int i = 0; i < 16; ++i) {
        pack[2 * i]     = f2bf(acc[i].x * sc) | (f2bf(acc[i].y * sc) << 16);
        pack[2 * i + 1] = f2bf(acc[i].z * sc) | (f2bf(acc[i].w * sc) << 16);
    }
    uint4* hr = reinterpret_cast<uint4*>(hs + (size_t)row * 32);
    #pragma unroll
    for (int i = 0; i < 8; ++i) hr[i] = reinterpret_cast<const uint4*>(pack)[i];
}

// ---- gather: 8-lane group/dst, depth-8, prefetched csr, shfl-reduced BN ---
__global__ __launch_bounds__(256) void k_gather_bn(const uint32_t* __restrict__ hsu,
                                                   const float* __restrict__ dinv,
                                                   const uint32_t* __restrict__ rowptr,
                                                   const uint32_t* __restrict__ csr,
                                                   const uint32_t* __restrict__ perm,
                                                   const float* __restrict__ b,
                                                   float* __restrict__ out,
                                                   float* __restrict__ sums) {
    const int tid = threadIdx.x;
    const int grp = tid >> 3;            // 0..31: one dst node per 8-lane group
    const int sub = tid & 7;             // dims sub*8 .. sub*8+7
    float bb[8];
    {
        const float4 b0 = *reinterpret_cast<const float4*>(&b[sub * 8]);
        const float4 b1 = *reinterpret_cast<const float4*>(&b[sub * 8 + 4]);
        bb[0] = b0.x; bb[1] = b0.y; bb[2] = b0.z; bb[3] = b0.w;
        bb[4] = b1.x; bb[5] = b1.y; bb[6] = b1.z; bb[7] = b1.w;
    }
    float regS[8], regQ[8];
    #pragma unroll
    for (int k = 0; k < 8; ++k) { regS[k] = 0.f; regQ[k] = 0.f; }

    // pairing: block i handles perm-group i (light) and NQ-1-i (heavy)
    #pragma unroll
    for (int it = 0; it < 2; ++it) {
        const int q = it ? (NQ - 1 - (int)blockIdx.x) : (int)blockIdx.x;
        if (it && q <= (int)blockIdx.x) break;           // middle group once
        const int d = (int)perm[q * 32 + grp];
        const uint32_t beg = rowptr[d], end = rowptr[d + 1];
        float a[8];
        {
            const uint4 sv = *reinterpret_cast<const uint4*>(&hsu[(size_t)d * 32 + sub * 4]);
            a[0] = bfl(sv.x); a[1] = bfh(sv.x); a[2] = bfl(sv.y); a[3] = bfh(sv.y);
            a[4] = bfl(sv.z); a[5] = bfh(sv.z); a[6] = bfl(sv.w); a[7] = bfh(sv.w);
        }
        uint32_t j = beg;
        uint32_t sj = (beg + (uint32_t)sub < end) ? csr[beg + (uint32_t)sub] : 0u;
        while (j + 8 <= end) {                           // depth-8 batches
            const uint32_t jn = j + 8;
            const uint32_t sj_next = (jn + (uint32_t)sub < end) ? csr[jn + (uint32_t)sub] : 0u;
            uint4 v[8];
            #pragma unroll
            for (int k = 0; k < 8; ++k) {
                const int s = __shfl((int)sj, k, 8);     // group-local broadcast
                v[k] = *reinterpret_cast<const uint4*>(&hsu[(size_t)s * 32 + sub * 4]);
            }
            #pragma unroll
            for (int k = 0; k < 8; ++k) {
                a[0] += bfl(v[k].x); a[1] += bfh(v[k].x);
                a[2] += bfl(v[k].y); a[3] += bfh(v[k].y);
                a[4] += bfl(v[k].z); a[5] += bfh(v[k].z);
                a[6] += bfl(v[k].w); a[7] += bfh(v[k].w);
            }
            sj = sj_next;
            j = jn;
        }
        if (j < end) {                                   // tail < 8 (sj preloaded)
            const int r = (int)(end - j);
            for (int k = 0; k < r; ++k) {
                const int s = __shfl((int)sj, k, 8);
                const uint4 vv = *reinterpret_cast<const uint4*>(&hsu[(size_t)s * 32 + sub * 4]);
                a[0] += bfl(vv.x); a[1] += bfh(vv.x);
                a[2] += bfl(vv.y); a[3] += bfh(vv.y);
                a[4] += bfl(vv.z); a[5] += bfh(vv.z);
                a[6] += bfl(vv.w); a[7] += bfh(vv.w);
            }
        }
        const float dd = dinv[d];
        float o[8];
        #pragma unroll
        for (int k = 0; k < 8; ++k) {
            o[k] = a[k] * dd + bb[k];
            regS[k] += o[k]; regQ[k] += o[k] * o[k];
        }
        const float4 o0 = make_float4(o[0], o[1], o[2], o[3]);
        const float4 o1 = make_float4(o[4], o[5], o[6], o[7]);
        *reinterpret_cast<float4*>(&out[(size_t)d * 64 + sub * 8])     = o0;
        *reinterpret_cast<float4*>(&out[(size_t)d * 64 + sub * 8 + 4]) = o1;
    }
    // cross-group (within-wave) reduce via shfl_xor; lanes grp*8+sub
    #pragma unroll
    for (int k = 0; k < 8; ++k) {
        regS[k] += __shfl_xor(regS[k], 8);
        regS[k] += __shfl_xor(regS[k], 16);
        regS[k] += __shfl_xor(regS[k], 32);
        regQ[k] += __shfl_xor(regQ[k], 8);
        regQ[k] += __shfl_xor(regQ[k], 16);
        regQ[k] += __shfl_xor(regQ[k], 32);
    }
    __shared__ float lsS[4][64], lsQ[4][64];     // 2 KB total
    const int wv = tid >> 6;
    const int lane = tid & 63;
    if (lane < 8) {                               // group-in-wave 0: lane == sub
        #pragma unroll
        for (int k = 0; k < 8; ++k) {
            lsS[wv][lane * 8 + k] = regS[k];
            lsQ[wv][lane * 8 + k] = regQ[k];
        }
    }
    __syncthreads();
    if (tid < 64) {
        const float s  = lsS[0][tid] + lsS[1][tid] + lsS[2][tid] + lsS[3][tid];
        const float qq = lsQ[0][tid] + lsQ[1][tid] + lsQ[2][tid] + lsQ[3][tid];
        atomicAdd(&sums[tid], s);
        atomicAdd(&sums[64 + tid], qq);
    }
}

// ---- fused BN-finalize + BN-apply + dropout (threefry, XOR fold) + ReLU ----
__global__ __launch_bounds__(256) void k_bn_drop_relu(float* __restrict__ out,
                                                      const float* __restrict__ sums,
                                                      const float* __restrict__ gamma,
                                                      const float* __restrict__ beta) {
    __shared__ float ls_sc[64], ls_sh[64];
    const int tid = threadIdx.x;
    if (tid < 64) {
        const float mean = sums[tid] * (1.0f / (float)N);
        const float var  = sums[64 + tid] * (1.0f / (float)N) - mean * mean;
        const float rstd = rsqrtf(var + EPS);
        const float sc = gamma[tid] * rstd;
        ls_sc[tid] = sc;
        ls_sh[tid] = beta[tid] - mean * sc;
    }
    __syncthreads();
    const int base = (blockIdx.x * 256 + tid) * 2;    // grid covers N*D/2 threads
    uint32_t p0 = 0u, p1 = (uint32_t)base;
    threefry2x32_k42(p0, p1);
    const uint32_t bits0 = p0 ^ p1;
    uint32_t q0 = 0u, q1 = (uint32_t)(base + 1);
    threefry2x32_k42(q0, q1);
    const uint32_t bits1 = q0 ^ q1;
    const int c0 = base & 63;                          // even; c1 = c0+1
    float2 v = *reinterpret_cast<const float2*>(&out[base]);
    v.x = v.x * ls_sc[c0]     + ls_sh[c0];
    v.y = v.y * ls_sc[c0 + 1] + ls_sh[c0 + 1];
    const float u0 = __uint_as_float((bits0 >> 9) | 0x3F800000u) - 1.0f;
    const float u1 = __uint_as_float((bits1 >> 9) | 0x3F800000u) - 1.0f;
    v.x = (u0 < 0.9f) ? v.x * (1.0f / 0.9f) : 0.0f;
    v.y = (u1 < 0.9f) ? v.y * (1.0f / 0.9f) : 0.0f;
    v.x = fmaxf(v.x, 0.f);
    v.y = fmaxf(v.y, 0.f);
    *reinterpret_cast<float2*>(&out[base]) = v;
}

// ---------------------------------------------------------------------------
extern "C" void kernel_launch(void* const* d_in, const int* in_sizes, int n_in,
                              void* d_out, int out_size, void* d_ws, size_t ws_size,
                              hipStream_t stream) {
    const float*    x     = (const float*)d_in[0];
    const uint32_t* ei    = (const uint32_t*)d_in[1];
    const float*    W     = (const float*)d_in[2];
    const float*    b     = (const float*)d_in[3];
    const float*    gamma = (const float*)d_in[4];
    const float*    beta  = (const float*)d_in[5];
    float* out = (float*)d_out;

    uint32_t* hs      = (uint32_t*)d_ws;               // N*32 u32 (bf16 rows, 12.8 MB)
    float*    dinv    = (float*)(hs + (size_t)N * 32); // N f32
    float*    sums    = (float*)(dinv + N);            // 128 f32 ← zero span (in mscan)
    uint32_t* dh      = (uint32_t*)(sums + 128);       // 128 degree histogram
    uint32_t* dcur    = dh + 128;                      // 128 degree cursors
    uint32_t* bptr    = dcur + 128;                    // NBKT1+1 = 99
    uint32_t* cntM    = bptr + NBKT1 + 1;              // 25088 count matrix
    uint32_t* rowptr  = cntM + MTOT;                   // N+1
    uint32_t* perm    = rowptr + N + 1;                // N
    uint32_t* edata   = perm + N;                      // E (bucket-sorted packed)
    uint32_t* csr     = edata + E;                     // E   (total ≈ 24.5 MB)

    const int nb256 = (N + 255) / 256;                 // 391

    k_hist1<<<NBLK1, 256, 0, stream>>>(ei, cntM);
    k_mscan<<<1, 1024, 0, stream>>>(cntM, bptr, (uint32_t*)sums);
    k_flush1<<<NBLK1, 256, 0, stream>>>(ei, cntM, edata);
    k_csr2<<<NBKT1, 1024, 0, stream>>>(edata, bptr, csr, rowptr, dinv, dh);
    k_dscan<<<1, 128, 0, stream>>>(dh, dcur);
    k_perm<<<nb256, 256, 0, stream>>>(rowptr, dcur, perm);
    k_gemm<<<nb256, 256, 0, stream>>>(x, W, dinv, hs);
    k_gather_bn<<<GGRID, 256, 0, stream>>>(hs, dinv, rowptr, csr, perm, b, out, sums);
    k_bn_drop_relu<<<(N * D) / 512, 256, 0, stream>>>(out, sums, gamma, beta);
}